// Round 14
// baseline (457.988 us; speedup 1.0000x reference)
//
#include <hip/hip_runtime.h>
#include <hip/hip_bf16.h>
#include <stdint.h>

#define SEQ   2048
#define NBH   64      // B*H
#define DH    64
#define CH    1024
#define MTOT  8192    // B*SEQ
// 1/sqrt(64) * log2(e): QK^T is computed in log2 domain, softmax uses v_exp_f32 (2^x)
#define QSCALE 0.1803368801111204f

typedef __bf16 bf16_t;
typedef bf16_t bf16x8 __attribute__((ext_vector_type(8)));
typedef float  f32x4  __attribute__((ext_vector_type(4)));
typedef float  f32x16 __attribute__((ext_vector_type(16)));

__device__ __forceinline__ bf16_t to_bf16(float f) {
  uint32_t u = __builtin_bit_cast(uint32_t, f);
  uint16_t r = (uint16_t)((u + 0x7fffu + ((u >> 16) & 1u)) >> 16);
  return __builtin_bit_cast(bf16_t, r);
}

__device__ __forceinline__ void gload_lds16(const void* g, void* l) {
  __builtin_amdgcn_global_load_lds(
      (const __attribute__((address_space(1))) uint32_t*)g,
      (__attribute__((address_space(3))) uint32_t*)l, 16, 0, 0);
}

__device__ __forceinline__ f32x4 mfma_bf16(bf16x8 a, bf16x8 b, f32x4 c) {
  return __builtin_amdgcn_mfma_f32_16x16x32_bf16(a, b, c, 0, 0, 0);
}
__device__ __forceinline__ f32x16 mfma32_bf16(bf16x8 a, bf16x8 b, f32x16 c) {
  return __builtin_amdgcn_mfma_f32_32x32x16_bf16(a, b, c, 0, 0, 0);
}

__device__ __forceinline__ float exp2_fast(float x) {
#if __has_builtin(__builtin_amdgcn_exp2f)
  return __builtin_amdgcn_exp2f(x);
#else
  float r;
  asm("v_exp_f32 %0, %1\ns_nop 0" : "=v"(r) : "v"(x));
  return r;
#endif
}

// dst.lo16 = bf16(lo), dst.hi16 = bf16(hi), RNE
__device__ __forceinline__ uint32_t cvt_pk_bf16(float lo, float hi) {
  uint32_t r;
  asm("v_cvt_pk_bf16_f32 %0, %1, %2" : "=v"(r) : "v"(lo), "v"(hi));
  return r;
}

// After: a = {a.lanes0-31, b.lanes0-31}, b = {a.lanes32-63, b.lanes32-63}
__device__ __forceinline__ void permlane32_swap(uint32_t& a, uint32_t& b) {
  asm("s_nop 1\n\tv_permlane32_swap_b32 %0, %1\n\ts_nop 1" : "+v"(a), "+v"(b));
}

// ---------------- merged prep: x->bf16 cvt + both weight transposes ----------
// blocks [0,2048): cvt x (grid-stride, 16B stores); [2048,2816): w_qkv^T;
// [2816,3072): w_out^T
__global__ __launch_bounds__(256) void prep(
    const float* __restrict__ x, bf16_t* __restrict__ xb,
    const float* __restrict__ w_qkv, bf16_t* __restrict__ wqkvT,
    const float* __restrict__ w_out, bf16_t* __restrict__ woT) {
  __shared__ float t[64 * 65];
  const int tid = threadIdx.x;
  const int blk = blockIdx.x;
  if (blk < 2048) {
    int i = (blk * 256 + tid) * 8;
    const int stride = 2048 * 256 * 8;
    for (; i < MTOT * CH; i += stride) {
      const float4 f0 = *reinterpret_cast<const float4*>(x + i);
      const float4 f1 = *reinterpret_cast<const float4*>(x + i + 4);
      const uint4 pk = make_uint4(cvt_pk_bf16(f0.x, f0.y), cvt_pk_bf16(f0.z, f0.w),
                                  cvt_pk_bf16(f1.x, f1.y), cvt_pk_bf16(f1.z, f1.w));
      *reinterpret_cast<uint4*>(xb + i) = pk;
    }
    return;
  }
  const float* W; bf16_t* WT; int Nd, nx, bi;
  if (blk < 2048 + 768) { bi = blk - 2048; W = w_qkv; WT = wqkvT; Nd = 3 * CH; nx = 48; }
  else                  { bi = blk - 2816; W = w_out; WT = woT;   Nd = CH;     nx = 16; }
  const int n0 = (bi % nx) * 64, k0 = (bi / nx) * 64;
#pragma unroll
  for (int rr = 0; rr < 16; ++rr) {
    const int idx = rr * 256 + tid;
    const int r = idx >> 6, c = idx & 63;
    t[r * 65 + c] = W[(size_t)(k0 + r) * Nd + n0 + c];
  }
  __syncthreads();
#pragma unroll
  for (int rr = 0; rr < 16; ++rr) {
    const int idx = rr * 256 + tid;
    const int nr = idx >> 6, kc = idx & 63;
    WT[(size_t)(n0 + nr) * CH + k0 + kc] = to_bf16(t[kc * 65 + nr]);
  }
}

// ------------- QKV GEMM: faithful 8-phase 256x256, derived counted waits -----
// A [8192][1024] x BT [3072][1024] -> Q (log2-scaled), K, V^T.
// 8 waves (wr=2 x wc=4), per-wave C = 128x64 (8 m-frags x 4 n-frags).
// K-step BK=64, double-buffered LDS (128 KB), 4 phases/K-step:
//   P(mh,nh): 12 ds_read_b128 + stage 1 half-tile (2 gload_lds) + 16 MFMA.
// Half-tiles grouped by PHASE NEED:
//   A-half mh = rows {wr*128 + mh*64 + [0,64) : wr 0,1}  (16 KB)
//   B-half nh = rows {wc*64  + nh*32 + [0,32) : wc 0..3} (16 KB)
// Stage order per K-step t (into buf t^1, for step t+1): A0, B0, A1, B1.
// FIFO vmcnt accounting (2 loads/unit), steady state at phase entry:
//   P1 out={A0,B0,A1,B1}=8  need A0,B0 -> vmcnt(4); issues A0' -> 6
//   P2 out={A1,B1,A0'}=6    need A1    -> vmcnt(4); issues B0' -> 6
//   P3 out={B1,A0',B0'}=6   need B1    -> vmcnt(4); issues A1' -> 6
//   P4 (all forced)         no wait   ; issues B1' -> 8  (= P1 precondition)
// Last K-step (no staging): waits 4 / 2 / 0 / none.
// One vmcnt+s_barrier per phase: bodies are lockstep-bounded, reads hit
// buf[t&1], stage DMA hits buf[t&1 ^ 1] -> WAR-safe.
__global__ __launch_bounds__(512, 1) void gemm8p_qkv(
    const bf16_t* __restrict__ A, const bf16_t* __restrict__ BT,
    bf16_t* __restrict__ qb, bf16_t* __restrict__ kb, bf16_t* __restrict__ vb) {
  __shared__ __attribute__((aligned(16))) bf16_t lA[2][2][128 * 64];  // 64 KB
  __shared__ __attribute__((aligned(16))) bf16_t lB[2][2][128 * 64];  // 64 KB
  const int tid = threadIdx.x;        // 0..511
  const int lane = tid & 63;
  const int wv = tid >> 6;            // 0..7
  const int wr = wv >> 2, wc = wv & 3;
  const int l15 = lane & 15, l16 = lane >> 4;

  // XCD-aware bijective swizzle (384 % 8 == 0)
  const int nwg = gridDim.x;
  int bid = blockIdx.x;
  bid = (bid & 7) * (nwg >> 3) + (bid >> 3);
  const int m0 = (bid / 12) * 256, n0 = (bid % 12) * 256;

  f32x4 acc[8][4] = {};   // [mh*4+i][nh*2+j]

  const int srow = tid >> 3;          // 0..63
  const int sch = tid & 7;

  auto stageA = [&](int pb, int mh, int kt) {
#pragma unroll
    for (int l = 0; l < 2; ++l) {
      const int q = l * 64 + srow;                       // local row in half
      const int grow = m0 + ((q >> 6) << 7) + mh * 64 + (q & 63);
      const int cs = sch ^ (q & 7);
      gload_lds16(A + (size_t)grow * CH + kt + cs * 8,
                  reinterpret_cast<char*>(&lA[pb][mh][0]) + l * 8192 + tid * 16);
    }
  };
  auto stageB = [&](int pb, int nh, int kt) {
#pragma unroll
    for (int l = 0; l < 2; ++l) {
      const int q = l * 64 + srow;
      const int grow = n0 + ((q >> 5) << 6) + nh * 32 + (q & 31);
      const int cs = sch ^ (q & 7);
      gload_lds16(BT + (size_t)grow * CH + kt + cs * 8,
                  reinterpret_cast<char*>(&lB[pb][nh][0]) + l * 8192 + tid * 16);
    }
  };

#define VMB(N) asm volatile("s_waitcnt vmcnt(" #N ")\n\ts_barrier" ::: "memory")
#define BARO() asm volatile("s_barrier" ::: "memory")

  // PHASE(pb, MH, NH): 12 ds_reads, then STAGE_STMT, then 16 MFMA
#define PHASE(PB, MH, NH, STAGE_STMT)                                          \
  {                                                                            \
    const bf16_t* Ab_ = &lA[PB][MH][0];                                        \
    const bf16_t* Bb_ = &lB[PB][NH][0];                                        \
    bf16x8 af_[4][2], bf_[2][2];                                               \
    _Pragma("unroll") for (int i = 0; i < 4; ++i) {                            \
      const int q = wr * 64 + i * 16 + l15;                                    \
      _Pragma("unroll") for (int kk = 0; kk < 2; ++kk) {                       \
        const int ch = (kk * 4 + l16) ^ (q & 7);                               \
        af_[i][kk] = *reinterpret_cast<const bf16x8*>(&Ab_[q * 64 + ch * 8]);  \
      }                                                                        \
    }                                                                          \
    _Pragma("unroll") for (int j = 0; j < 2; ++j) {                            \
      const int q = wc * 32 + j * 16 + l15;                                    \
      _Pragma("unroll") for (int kk = 0; kk < 2; ++kk) {                       \
        const int ch = (kk * 4 + l16) ^ (q & 7);                               \
        bf_[j][kk] = *reinterpret_cast<const bf16x8*>(&Bb_[q * 64 + ch * 8]);  \
      }                                                                        \
    }                                                                          \
    STAGE_STMT;                                                                \
    __builtin_amdgcn_s_setprio(1);                                             \
    _Pragma("unroll") for (int i = 0; i < 4; ++i)                              \
      _Pragma("unroll") for (int j = 0; j < 2; ++j) {                          \
        acc[MH * 4 + i][NH * 2 + j] =                                          \
            mfma_bf16(af_[i][0], bf_[j][0], acc[MH * 4 + i][NH * 2 + j]);      \
        acc[MH * 4 + i][NH * 2 + j] =                                          \
            mfma_bf16(af_[i][1], bf_[j][1], acc[MH * 4 + i][NH * 2 + j]);      \
      }                                                                        \
    __builtin_amdgcn_s_setprio(0);                                             \
  }

  // prologue: step 0's four units, in steady-state order
  stageA(0, 0, 0);
  stageB(0, 0, 0);
  stageA(0, 1, 0);
  stageB(0, 1, 0);

  for (int kt = 0; kt < 15; ++kt) {
    const int pb = kt & 1, pn = pb ^ 1;
    const int kn = (kt + 1) * 64;
    if (pb == 0) {
      VMB(4); PHASE(0, 0, 0, stageA(1, 0, kn));
      VMB(4); PHASE(0, 1, 0, stageB(1, 0, kn));
      VMB(4); PHASE(0, 0, 1, stageA(1, 1, kn));
      BARO(); PHASE(0, 1, 1, stageB(1, 1, kn));
    } else {
      VMB(4); PHASE(1, 0, 0, stageA(0, 0, kn));
      VMB(4); PHASE(1, 1, 0, stageB(0, 0, kn));
      VMB(4); PHASE(1, 0, 1, stageA(0, 1, kn));
      BARO(); PHASE(1, 1, 1, stageB(0, 1, kn));
    }
  }
  // peeled last K-step (kt = 15, pb = 1): drain 4 -> 2 -> 0
  VMB(4); PHASE(1, 0, 0, );
  VMB(2); PHASE(1, 1, 0, );
  VMB(0); PHASE(1, 0, 1, );
  BARO(); PHASE(1, 1, 1, );

#undef PHASE
#undef VMB
#undef BARO

  // epilogue: scatter to Q (scaled), K, V^T
  const int three = n0 >> 10;   // block-uniform (256-tile inside one 1024 section)
  if (three < 2) {
#pragma unroll
    for (int mf = 0; mf < 8; ++mf) {
#pragma unroll
      for (int nf = 0; nf < 4; ++nf) {
#pragma unroll
        for (int r = 0; r < 4; ++r) {
          const int m = m0 + wr * 128 + (mf >> 2) * 64 + (mf & 3) * 16 + l16 * 4 + r;
          const int f = n0 + wc * 64 + (nf >> 1) * 32 + (nf & 1) * 16 + l15;
          const int h = (f >> 6) & 15, d = f & 63;
          const int bh = (m >> 11) * 16 + h;
          const int n = m & 2047;
          const float val = acc[mf][nf][r];
          if (three == 0)
            qb[((size_t)bh * SEQ + n) * DH + d] = to_bf16(val * QSCALE);
          else
            kb[((size_t)bh * SEQ + n) * DH + d] = to_bf16(val);
        }
      }
    }
  } else {
    // V^T: 4 consecutive n (r=0..3) at fixed d -> one packed 8B store
#pragma unroll
    for (int mf = 0; mf < 8; ++mf) {
#pragma unroll
      for (int nf = 0; nf < 4; ++nf) {
        const int m = m0 + wr * 128 + (mf >> 2) * 64 + (mf & 3) * 16 + l16 * 4;
        const int f = n0 + wc * 64 + (nf >> 1) * 32 + (nf & 1) * 16 + l15;
        const int h = (f >> 6) & 15, d = f & 63;
        const int bh = (m >> 11) * 16 + h;
        const int n = m & 2047;
        const uint2 pk = make_uint2(cvt_pk_bf16(acc[mf][nf][0], acc[mf][nf][1]),
                                    cvt_pk_bf16(acc[mf][nf][2], acc[mf][nf][3]));
        *reinterpret_cast<uint2*>(&vb[((size_t)bh * DH + d) * SEQ + n]) = pk;
      }
    }
  }
}

// ---------------- out-proj GEMM (proven m97-style 128x128) -------------------
__global__ __launch_bounds__(256, 3) void gemm_out(
    const bf16_t* __restrict__ A, const bf16_t* __restrict__ BT, int K, int nx,
    const float* __restrict__ bias, float* __restrict__ out) {
  __shared__ __attribute__((aligned(16))) bf16_t lA[128 * 64];
  __shared__ __attribute__((aligned(16))) bf16_t lB[128 * 64];
  const int tid = threadIdx.x;
  const int lane = tid & 63;
  const int wv = tid >> 6;
  const int wm = wv >> 1, wn = wv & 1;

  const int nwg = gridDim.x;
  int bid = blockIdx.x;
  bid = (bid & 7) * (nwg >> 3) + (bid >> 3);
  const int m0 = (bid / nx) * 128, n0 = (bid % nx) * 128;

  const int l15 = lane & 15, l16 = lane >> 4;

  f32x4 acc[4][4] = {};

  const int srow = tid >> 3;
  const int sch = tid & 7;

  for (int kt = 0; kt < K; kt += 64) {
#pragma unroll
    for (int c = 0; c < 4; ++c) {
      const int row = c * 32 + srow;
      const int cs = sch ^ (row & 7);
      gload_lds16(A + (size_t)(m0 + row) * K + kt + cs * 8, &lA[c * 2048 + tid * 8]);
    }
#pragma unroll
    for (int c = 0; c < 4; ++c) {
      const int row = c * 32 + srow;
      const int cs = sch ^ (row & 7);
      gload_lds16(BT + (size_t)(n0 + row) * K + kt + cs * 8, &lB[c * 2048 + tid * 8]);
    }
    __syncthreads();
#pragma unroll
    for (int ks = 0; ks < 2; ++ks) {
      bf16x8 af[4], bfr[4];
#pragma unroll
      for (int i = 0; i < 4; ++i) {
        const int ar = wm * 64 + i * 16 + l15;
        const int cha = (ks * 4 + l16) ^ (ar & 7);
        af[i] = *reinterpret_cast<const bf16x8*>(&lA[ar * 64 + cha * 8]);
        const int br = wn * 64 + i * 16 + l15;
        const int chb = (ks * 4 + l16) ^ (br & 7);
        bfr[i] = *reinterpret_cast<const bf16x8*>(&lB[br * 64 + chb * 8]);
      }
#pragma unroll
      for (int i = 0; i < 4; ++i)
#pragma unroll
        for (int j = 0; j < 4; ++j)
          acc[i][j] = mfma_bf16(af[i], bfr[j], acc[i][j]);
    }
    __syncthreads();
  }

#pragma unroll
  for (int j = 0; j < 4; ++j) {
    const int cc = n0 + wn * 64 + j * 16 + l15;
    const float bb = bias[cc];
#pragma unroll
    for (int i = 0; i < 4; ++i) {
#pragma unroll
      for (int r = 0; r < 4; ++r) {
        const int m = m0 + wm * 64 + i * 16 + l16 * 4 + r;
        out[(size_t)m * CH + cc] = acc[i][j][r] + bb;
      }
    }
  }
}

// ---------------- flash attention (32x32 MFMA, in-register P via permlane) ----
// grid = 1024 (XCD-swizzled), block = 256 (4 waves x 32 q-rows)
// Proven-best structure (81 us): 2-buffer K/V, __syncthreads per tile.
__global__ __launch_bounds__(256, 4) void attn_fwd(
    const bf16_t* __restrict__ Q, const bf16_t* __restrict__ K,
    const bf16_t* __restrict__ V, bf16_t* __restrict__ O) {
  __shared__ __attribute__((aligned(16))) bf16_t lK[2][64 * 64];
  __shared__ __attribute__((aligned(16))) bf16_t lV[2][64 * 64];   // V^T tile [d][kt]
  const int tid = threadIdx.x;
  const int lane = tid & 63;
  const int wv = tid >> 6;
  const int l31 = lane & 31, hi = lane >> 5;

  // XCD swizzle: each XCD owns 8 consecutive bh (K/V footprint 4MB = one L2)
  const int lin = blockIdx.x;
  const int bh = (lin & 7) * 8 + ((lin >> 3) & 7);
  const int qb = lin >> 6;
  const int q0w = qb * 128 + wv * 32;

  const bf16_t* Qb = Q + (size_t)bh * SEQ * DH;
  const bf16_t* Kb = K + (size_t)bh * SEQ * DH;
  const bf16_t* Vb = V + (size_t)bh * DH * SEQ;

  // Q fragments (B-operand of 32x32x16): lane holds Q[q0w + l31][ks*16 + hi*8 + j]
  bf16x8 qf[4];
#pragma unroll
  for (int ks = 0; ks < 4; ++ks)
    qf[ks] = *reinterpret_cast<const bf16x8*>(
        Qb + (size_t)(q0w + l31) * DH + ks * 16 + hi * 8);

  f32x16 o0 = {}, o1 = {};   // O[q=crow(r,hi)][d = db*32 + l31]
  float rs0 = 0.f, rs1 = 0.f, rs2 = 0.f, rs3 = 0.f;  // partial denoms (q = l31)

  const int srow = tid >> 3;
  const int sch = tid & 7;

  auto stage = [&](int buf, int kt0) {
#pragma unroll
    for (int c = 0; c < 2; ++c) {
      const int row = c * 32 + srow;
      const int cs = sch ^ (row & 7);
      gload_lds16(Kb + (size_t)(kt0 + row) * DH + cs * 8,
                  reinterpret_cast<char*>(&lK[buf][0]) + c * 4096 + tid * 16);
      gload_lds16(Vb + (size_t)row * SEQ + kt0 + cs * 8,
                  reinterpret_cast<char*>(&lV[buf][0]) + c * 4096 + tid * 16);
    }
  };

  stage(0, 0);
  __syncthreads();
  int cur = 0;

  for (int t = 0; t < SEQ / 64; ++t) {
    if (t + 1 < SEQ / 64) stage(cur ^ 1, (t + 1) * 64);

    // S^T = K * Q^T : s0 = k-rows [0,32), s1 = [32,64); col q = l31
    f32x16 s0 = {}, s1 = {};
    __builtin_amdgcn_s_setprio(1);
#pragma unroll
    for (int ks = 0; ks < 4; ++ks) {
      {
        const int row = l31;
        const int ch = (ks * 2 + hi) ^ (row & 7);
        const bf16x8 kf = *reinterpret_cast<const bf16x8*>(
            reinterpret_cast<const char*>(&lK[cur][0]) + row * 128 + ch * 16);
        s0 = mfma32_bf16(kf, qf[ks], s0);
      }
      {
        const int row = 32 + l31;
        const int ch = (ks * 2 + hi) ^ (row & 7);
        const bf16x8 kf = *reinterpret_cast<const bf16x8*>(
            reinterpret_cast<const char*>(&lK[cur][0]) + row * 128 + ch * 16);
        s1 = mfma32_bf16(kf, qf[ks], s1);
      }
    }
    __builtin_amdgcn_s_setprio(0);

    // P = 2^S in place + 4-way partial row-sums (own k-half of column q=l31)
#pragma unroll
    for (int j = 0; j < 16; j += 4) {
      s0[j]     = exp2_fast(s0[j]);     rs0 += s0[j];
      s0[j + 1] = exp2_fast(s0[j + 1]); rs1 += s0[j + 1];
      s0[j + 2] = exp2_fast(s0[j + 2]); rs2 += s0[j + 2];
      s0[j + 3] = exp2_fast(s0[j + 3]); rs3 += s0[j + 3];
    }
#pragma unroll
    for (int j = 0; j < 16; j += 4) {
      s1[j]     = exp2_fast(s1[j]);     rs0 += s1[j];
      s1[j + 1] = exp2_fast(s1[j + 1]); rs1 += s1[j + 1];
      s1[j + 2] = exp2_fast(s1[j + 2]); rs2 += s1[j + 2];
      s1[j + 3] = exp2_fast(s1[j + 3]); rs3 += s1[j + 3];
    }

    // cvt_pk + permlane32_swap -> 4 PV A-fragments (k = 0..63)
    bf16x8 pa[4];
    {
      uint32_t a0 = cvt_pk_bf16(s0[0], s0[1]),   b0 = cvt_pk_bf16(s0[4], s0[5]);
      uint32_t a1 = cvt_pk_bf16(s0[2], s0[3]),   b1 = cvt_pk_bf16(s0[6], s0[7]);
      uint32_t a2 = cvt_pk_bf16(s0[8], s0[9]),   b2 = cvt_pk_bf16(s0[12], s0[13]);
      uint32_t a3 = cvt_pk_bf16(s0[10], s0[11]), b3 = cvt_pk_bf16(s0[14], s0[15]);
      permlane32_swap(a0, b0);
      permlane32_swap(a1, b1);
      permlane32_swap(a2, b2);
      permlane32_swap(a3, b3);
      union { uint32_t u[4]; bf16x8 v; } ua, ub, uc, ud;
      ua.u[0] = a0; ua.u[1] = a1; ua.u[2] = b0; ua.u[3] = b1; pa[0] = ua.v;
      ub.u[0] = a2; ub.u[1] = a3; ub.u[2] = b2; ub.u[3] = b3; pa[1] = ub.v;
      uint32_t c0 = cvt_pk_bf16(s1[0], s1[1]),   d0 = cvt_pk_bf16(s1[4], s1[5]);
      uint32_t c1 = cvt_pk_bf16(s1[2], s1[3]),   d1 = cvt_pk_bf16(s1[6], s1[7]);
      uint32_t c2 = cvt_pk_bf16(s1[8], s1[9]),   d2 = cvt_pk_bf16(s1[12], s1[13]);
      uint32_t c3 = cvt_pk_bf16(s1[10], s1[11]), d3 = cvt_pk_bf16(s1[14], s1[15]);
      permlane32_swap(c0, d0);
      permlane32_swap(c1, d1);
      permlane32_swap(c2, d2);
      permlane32_swap(c3, d3);
      uc.u[0] = c0; uc.u[1] = c1; uc.u[2] = d0; uc.u[3] = d1; pa[2] = uc.v;
      ud.u[0] = c2; ud.u[1] = c3; ud.u[2] = d2; ud.u[3] = d3; pa[3] = ud.v;
    }

    // O += P * V  (B-operand: lane holds V^T[db*32 + l31][tt*16 + hi*8 + j])
    __builtin_amdgcn_s_setprio(1);
#pragma unroll
    for (int tt = 0; tt < 4; ++tt) {
      {
        const int row = l31;
        const int ch = (tt * 2 + hi) ^ (row & 7);
        const bf16x8 vf = *reinterpret_cast<const bf16x8*>(
            reinterpret_cast<const char*>(&lV[cur][0]) + row * 128 + ch * 16);
        o0 = mfma32_bf16(pa[tt], vf, o0);
      }
      {
        const int row = 32 + l31;
        const int ch = (tt * 2 + hi) ^ (row & 7);
        const bf16x8 vf = *reinterpret_cast<const bf16x8*>(
            reinterpret_cast<const char*>(&lV[cur][0]) + row * 128 + ch * 16);
        o1 = mfma32_bf16(pa[tt], vf, o1);
      }
    }
    __builtin_amdgcn_s_setprio(0);

    __syncthreads();
    cur ^= 1;
  }

  // combine the two k-halves of the denominator (lane l <-> l^32, same q)
  const float rs = (rs0 + rs1) + (rs2 + rs3);
  uint32_t ra = __builtin_bit_cast(uint32_t, rs), rb2 = ra;
  permlane32_swap(ra, rb2);
  const float tot = __builtin_bit_cast(float, ra) + __builtin_bit_cast(float, rb2);
  const float rinv = 1.0f / tot;

  const int b = bh >> 4, h = bh & 15;
#pragma unroll
  for (int r = 0; r < 16; ++r) {
    const int qr = (r & 3) + 8 * (r >> 2) + 4 * hi;
    const float inv = __shfl(rinv, qr, 64);   // lane qr holds denom for row qr
    const size_t grow = (size_t)(b * SEQ + q0w + qr) * CH + h * DH;
    O[grow + l31]      = to_bf16(o0[r] * inv);
    O[grow + 32 + l31] = to_bf16(o1[r] * inv);
  }
}

// ---------------- launch ----------------

extern "C" void kernel_launch(void* const* d_in, const int* in_sizes, int n_in,
                              void* d_out, int out_size, void* d_ws, size_t ws_size,
                              hipStream_t stream) {
  const float* x     = (const float*)d_in[0];
  const float* w_qkv = (const float*)d_in[1];
  const float* w_out = (const float*)d_in[2];
  const float* b_out = (const float*)d_in[3];
  float* out = (float*)d_out;

  char* ws = (char*)d_ws;
  bf16_t* xb    = (bf16_t*)(ws);                       // 16 MB  [8192][1024]
  bf16_t* wqkvT = (bf16_t*)(ws + 16777216);            // 6 MB   [3072][1024]
  bf16_t* woT   = (bf16_t*)(ws + 23068672);            // 2 MB   [1024][1024]
  bf16_t* Qb    = (bf16_t*)(ws + 25165824);            // 16 MB  [64][2048][64]
  bf16_t* Kb    = (bf16_t*)(ws + 41943040);            // 16 MB  [64][2048][64]
  bf16_t* Vb    = (bf16_t*)(ws + 58720256);            // 16 MB  [64][64][2048]
  bf16_t* Ab    = xb;                                  // alias: x no longer needed post-QKV

  prep<<<3072, 256, 0, stream>>>(x, xb, w_qkv, wqkvT, w_out, woT);

  gemm8p_qkv<<<(MTOT / 256) * (3 * CH / 256), 512, 0, stream>>>(
      xb, wqkvT, Qb, Kb, Vb);

  attn_fwd<<<1024, 256, 0, stream>>>(Qb, Kb, Vb, Ab);

  gemm_out<<<(CH / 128) * (MTOT / 128), 256, 0, stream>>>(
      Ab, woT, CH, CH / 128, b_out, out);
}

// Round 15
// 166.245 us; speedup vs baseline: 2.7549x; 2.7549x over previous
//
#include <hip/hip_runtime.h>
#include <hip/hip_bf16.h>
#include <stdint.h>

#define SEQ   2048
#define NBH   64      // B*H
#define DH    64
#define CH    1024
#define MTOT  8192    // B*SEQ
// 1/sqrt(64) * log2(e): QK^T is computed in log2 domain, softmax uses v_exp_f32 (2^x)
#define QSCALE 0.1803368801111204f

typedef __bf16 bf16_t;
typedef bf16_t bf16x8 __attribute__((ext_vector_type(8)));
typedef float  f32x4  __attribute__((ext_vector_type(4)));
typedef float  f32x16 __attribute__((ext_vector_type(16)));

__device__ __forceinline__ bf16_t to_bf16(float f) {
  uint32_t u = __builtin_bit_cast(uint32_t, f);
  uint16_t r = (uint16_t)((u + 0x7fffu + ((u >> 16) & 1u)) >> 16);
  return __builtin_bit_cast(bf16_t, r);
}

__device__ __forceinline__ void gload_lds16(const void* g, void* l) {
  __builtin_amdgcn_global_load_lds(
      (const __attribute__((address_space(1))) uint32_t*)g,
      (__attribute__((address_space(3))) uint32_t*)l, 16, 0, 0);
}

__device__ __forceinline__ f32x4 mfma_bf16(bf16x8 a, bf16x8 b, f32x4 c) {
  return __builtin_amdgcn_mfma_f32_16x16x32_bf16(a, b, c, 0, 0, 0);
}
__device__ __forceinline__ f32x16 mfma32_bf16(bf16x8 a, bf16x8 b, f32x16 c) {
  return __builtin_amdgcn_mfma_f32_32x32x16_bf16(a, b, c, 0, 0, 0);
}

__device__ __forceinline__ float exp2_fast(float x) {
#if __has_builtin(__builtin_amdgcn_exp2f)
  return __builtin_amdgcn_exp2f(x);
#else
  float r;
  asm("v_exp_f32 %0, %1\ns_nop 0" : "=v"(r) : "v"(x));
  return r;
#endif
}

// dst.lo16 = bf16(lo), dst.hi16 = bf16(hi), RNE
__device__ __forceinline__ uint32_t cvt_pk_bf16(float lo, float hi) {
  uint32_t r;
  asm("v_cvt_pk_bf16_f32 %0, %1, %2" : "=v"(r) : "v"(lo), "v"(hi));
  return r;
}

// After: a = {a.lanes0-31, b.lanes0-31}, b = {a.lanes32-63, b.lanes32-63}
__device__ __forceinline__ void permlane32_swap(uint32_t& a, uint32_t& b) {
  asm("s_nop 1\n\tv_permlane32_swap_b32 %0, %1\n\ts_nop 1" : "+v"(a), "+v"(b));
}

// ---------------- merged prep: x->bf16 cvt + both weight transposes ----------
// blocks [0,2048): cvt x (grid-stride, 16B stores); [2048,2816): w_qkv^T;
// [2816,3072): w_out^T
__global__ __launch_bounds__(256) void prep(
    const float* __restrict__ x, bf16_t* __restrict__ xb,
    const float* __restrict__ w_qkv, bf16_t* __restrict__ wqkvT,
    const float* __restrict__ w_out, bf16_t* __restrict__ woT) {
  __shared__ float t[64 * 65];
  const int tid = threadIdx.x;
  const int blk = blockIdx.x;
  if (blk < 2048) {
    int i = (blk * 256 + tid) * 8;
    const int stride = 2048 * 256 * 8;
    for (; i < MTOT * CH; i += stride) {
      const float4 f0 = *reinterpret_cast<const float4*>(x + i);
      const float4 f1 = *reinterpret_cast<const float4*>(x + i + 4);
      const uint4 pk = make_uint4(cvt_pk_bf16(f0.x, f0.y), cvt_pk_bf16(f0.z, f0.w),
                                  cvt_pk_bf16(f1.x, f1.y), cvt_pk_bf16(f1.z, f1.w));
      *reinterpret_cast<uint4*>(xb + i) = pk;
    }
    return;
  }
  const float* W; bf16_t* WT; int Nd, nx, bi;
  if (blk < 2048 + 768) { bi = blk - 2048; W = w_qkv; WT = wqkvT; Nd = 3 * CH; nx = 48; }
  else                  { bi = blk - 2816; W = w_out; WT = woT;   Nd = CH;     nx = 16; }
  const int n0 = (bi % nx) * 64, k0 = (bi / nx) * 64;
#pragma unroll
  for (int rr = 0; rr < 16; ++rr) {
    const int idx = rr * 256 + tid;
    const int r = idx >> 6, c = idx & 63;
    t[r * 65 + c] = W[(size_t)(k0 + r) * Nd + n0 + c];
  }
  __syncthreads();
#pragma unroll
  for (int rr = 0; rr < 16; ++rr) {
    const int idx = rr * 256 + tid;
    const int nr = idx >> 6, kc = idx & 63;
    WT[(size_t)(n0 + nr) * CH + k0 + kc] = to_bf16(t[kc * 65 + nr]);
  }
}

// ---------------- GEMM (A [M][K] x BT [N][K], both bf16) ----------------
// Proven m97-style 128x128 structure, 3 blocks/CU implicit overlap.
// EPI 0: scatter into Q (scaled to log2 domain), K, V^T buffers.  EPI 1: +bias, fp32 out.
// 1D grid, XCD-swizzled (nwg % 8 == 0), nx = N/128 column tiles.

template <int EPI>
__global__ __launch_bounds__(256, 3) void gemm_bt(
    const bf16_t* __restrict__ A, const bf16_t* __restrict__ BT, int K, int nx,
    bf16_t* __restrict__ qb, bf16_t* __restrict__ kb, bf16_t* __restrict__ vb,
    const float* __restrict__ bias, float* __restrict__ out) {
  __shared__ __attribute__((aligned(16))) bf16_t lA[128 * 64];
  __shared__ __attribute__((aligned(16))) bf16_t lB[128 * 64];
  const int tid = threadIdx.x;
  const int lane = tid & 63;
  const int wv = tid >> 6;
  const int wm = wv >> 1, wn = wv & 1;

  // XCD-aware bijective swizzle: each XCD gets a contiguous chunk of tiles
  const int nwg = gridDim.x;
  int bid = blockIdx.x;
  bid = (bid & 7) * (nwg >> 3) + (bid >> 3);
  const int m0 = (bid / nx) * 128, n0 = (bid % nx) * 128;

  const int l15 = lane & 15, l16 = lane >> 4;

  f32x4 acc[4][4] = {};

  const int srow = tid >> 3;      // 0..31
  const int sch = tid & 7;        // 16B chunk within 128B row

  for (int kt = 0; kt < K; kt += 64) {
#pragma unroll
    for (int c = 0; c < 4; ++c) {
      const int row = c * 32 + srow;
      const int cs = sch ^ (row & 7);            // pre-swizzled source chunk
      gload_lds16(A + (size_t)(m0 + row) * K + kt + cs * 8, &lA[c * 2048 + tid * 8]);
    }
#pragma unroll
    for (int c = 0; c < 4; ++c) {
      const int row = c * 32 + srow;
      const int cs = sch ^ (row & 7);
      gload_lds16(BT + (size_t)(n0 + row) * K + kt + cs * 8, &lB[c * 2048 + tid * 8]);
    }
    __syncthreads();
#pragma unroll
    for (int ks = 0; ks < 2; ++ks) {
      bf16x8 af[4], bfr[4];
#pragma unroll
      for (int i = 0; i < 4; ++i) {
        const int ar = wm * 64 + i * 16 + l15;
        const int cha = (ks * 4 + l16) ^ (ar & 7);
        af[i] = *reinterpret_cast<const bf16x8*>(&lA[ar * 64 + cha * 8]);
        const int br = wn * 64 + i * 16 + l15;
        const int chb = (ks * 4 + l16) ^ (br & 7);
        bfr[i] = *reinterpret_cast<const bf16x8*>(&lB[br * 64 + chb * 8]);
      }
#pragma unroll
      for (int i = 0; i < 4; ++i)
#pragma unroll
        for (int j = 0; j < 4; ++j)
          acc[i][j] = mfma_bf16(af[i], bfr[j], acc[i][j]);
    }
    __syncthreads();
  }

  if (EPI == 0) {
    const int f0 = n0 + wn * 64;
    const int three = f0 >> 10;   // block-uniform
    if (three < 2) {
#pragma unroll
      for (int i = 0; i < 4; ++i) {
#pragma unroll
      for (int j = 0; j < 4; ++j) {
#pragma unroll
          for (int r = 0; r < 4; ++r) {
            const int m = m0 + wm * 64 + i * 16 + l16 * 4 + r;
            const int f = f0 + j * 16 + l15;
            const int h = (f >> 6) & 15, d = f & 63;
            const int bh = (m >> 11) * 16 + h;
            const int n = m & 2047;
            const float val = acc[i][j][r];
            if (three == 0)
              qb[((size_t)bh * SEQ + n) * DH + d] = to_bf16(val * QSCALE);
            else
              kb[((size_t)bh * SEQ + n) * DH + d] = to_bf16(val);
          }
        }
      }
    } else {
      // V^T: 4 consecutive n (r=0..3) at fixed d -> one packed 8B store
#pragma unroll
      for (int i = 0; i < 4; ++i) {
#pragma unroll
        for (int j = 0; j < 4; ++j) {
          const int m = m0 + wm * 64 + i * 16 + l16 * 4;   // r=0
          const int f = f0 + j * 16 + l15;
          const int h = (f >> 6) & 15, d = f & 63;
          const int bh = (m >> 11) * 16 + h;
          const int n = m & 2047;
          const uint2 pk = make_uint2(cvt_pk_bf16(acc[i][j][0], acc[i][j][1]),
                                      cvt_pk_bf16(acc[i][j][2], acc[i][j][3]));
          *reinterpret_cast<uint2*>(&vb[((size_t)bh * DH + d) * SEQ + n]) = pk;
        }
      }
    }
  } else {
#pragma unroll
    for (int j = 0; j < 4; ++j) {
      const int cc = n0 + wn * 64 + j * 16 + l15;
      const float bb = bias[cc];
#pragma unroll
      for (int i = 0; i < 4; ++i) {
#pragma unroll
        for (int r = 0; r < 4; ++r) {
          const int m = m0 + wm * 64 + i * 16 + l16 * 4 + r;
          out[(size_t)m * CH + cc] = acc[i][j][r] + bb;
        }
      }
    }
  }
}

// ---------------- flash attention (32x32 MFMA, in-register P via permlane) ----
// grid = 1024 (XCD-swizzled), block = 256 (4 waves x 32 q-rows)
// Proven-best structure (81 us): 2-buffer K/V, __syncthreads per tile.
// rs kept as 4 partial accumulators to break the 32-deep serial VALU chain.
__global__ __launch_bounds__(256, 4) void attn_fwd(
    const bf16_t* __restrict__ Q, const bf16_t* __restrict__ K,
    const bf16_t* __restrict__ V, bf16_t* __restrict__ O) {
  __shared__ __attribute__((aligned(16))) bf16_t lK[2][64 * 64];
  __shared__ __attribute__((aligned(16))) bf16_t lV[2][64 * 64];   // V^T tile [d][kt]
  const int tid = threadIdx.x;
  const int lane = tid & 63;
  const int wv = tid >> 6;
  const int l31 = lane & 31, hi = lane >> 5;

  // XCD swizzle: each XCD owns 8 consecutive bh (K/V footprint 4MB = one L2)
  const int lin = blockIdx.x;
  const int bh = (lin & 7) * 8 + ((lin >> 3) & 7);
  const int qb = lin >> 6;
  const int q0w = qb * 128 + wv * 32;

  const bf16_t* Qb = Q + (size_t)bh * SEQ * DH;
  const bf16_t* Kb = K + (size_t)bh * SEQ * DH;
  const bf16_t* Vb = V + (size_t)bh * DH * SEQ;

  // Q fragments (B-operand of 32x32x16): lane holds Q[q0w + l31][ks*16 + hi*8 + j]
  bf16x8 qf[4];
#pragma unroll
  for (int ks = 0; ks < 4; ++ks)
    qf[ks] = *reinterpret_cast<const bf16x8*>(
        Qb + (size_t)(q0w + l31) * DH + ks * 16 + hi * 8);

  f32x16 o0 = {}, o1 = {};   // O[q=crow(r,hi)][d = db*32 + l31]
  float rs0 = 0.f, rs1 = 0.f, rs2 = 0.f, rs3 = 0.f;  // partial denoms (q = l31)

  const int srow = tid >> 3;
  const int sch = tid & 7;

  auto stage = [&](int buf, int kt0) {
#pragma unroll
    for (int c = 0; c < 2; ++c) {
      const int row = c * 32 + srow;
      const int cs = sch ^ (row & 7);
      gload_lds16(Kb + (size_t)(kt0 + row) * DH + cs * 8,
                  reinterpret_cast<char*>(&lK[buf][0]) + c * 4096 + tid * 16);
      gload_lds16(Vb + (size_t)row * SEQ + kt0 + cs * 8,
                  reinterpret_cast<char*>(&lV[buf][0]) + c * 4096 + tid * 16);
    }
  };

  stage(0, 0);
  __syncthreads();
  int cur = 0;

  for (int t = 0; t < SEQ / 64; ++t) {
    if (t + 1 < SEQ / 64) stage(cur ^ 1, (t + 1) * 64);

    // S^T = K * Q^T : s0 = k-rows [0,32), s1 = [32,64); col q = l31
    f32x16 s0 = {}, s1 = {};
    __builtin_amdgcn_s_setprio(1);
#pragma unroll
    for (int ks = 0; ks < 4; ++ks) {
      {
        const int row = l31;
        const int ch = (ks * 2 + hi) ^ (row & 7);
        const bf16x8 kf = *reinterpret_cast<const bf16x8*>(
            reinterpret_cast<const char*>(&lK[cur][0]) + row * 128 + ch * 16);
        s0 = mfma32_bf16(kf, qf[ks], s0);
      }
      {
        const int row = 32 + l31;
        const int ch = (ks * 2 + hi) ^ (row & 7);
        const bf16x8 kf = *reinterpret_cast<const bf16x8*>(
            reinterpret_cast<const char*>(&lK[cur][0]) + row * 128 + ch * 16);
        s1 = mfma32_bf16(kf, qf[ks], s1);
      }
    }
    __builtin_amdgcn_s_setprio(0);

    // P = 2^S in place + 4-way partial row-sums (own k-half of column q=l31)
#pragma unroll
    for (int j = 0; j < 16; j += 4) {
      s0[j]     = exp2_fast(s0[j]);     rs0 += s0[j];
      s0[j + 1] = exp2_fast(s0[j + 1]); rs1 += s0[j + 1];
      s0[j + 2] = exp2_fast(s0[j + 2]); rs2 += s0[j + 2];
      s0[j + 3] = exp2_fast(s0[j + 3]); rs3 += s0[j + 3];
    }
#pragma unroll
    for (int j = 0; j < 16; j += 4) {
      s1[j]     = exp2_fast(s1[j]);     rs0 += s1[j];
      s1[j + 1] = exp2_fast(s1[j + 1]); rs1 += s1[j + 1];
      s1[j + 2] = exp2_fast(s1[j + 2]); rs2 += s1[j + 2];
      s1[j + 3] = exp2_fast(s1[j + 3]); rs3 += s1[j + 3];
    }

    // cvt_pk + permlane32_swap -> 4 PV A-fragments (k = 0..63)
    bf16x8 pa[4];
    {
      uint32_t a0 = cvt_pk_bf16(s0[0], s0[1]),   b0 = cvt_pk_bf16(s0[4], s0[5]);
      uint32_t a1 = cvt_pk_bf16(s0[2], s0[3]),   b1 = cvt_pk_bf16(s0[6], s0[7]);
      uint32_t a2 = cvt_pk_bf16(s0[8], s0[9]),   b2 = cvt_pk_bf16(s0[12], s0[13]);
      uint32_t a3 = cvt_pk_bf16(s0[10], s0[11]), b3 = cvt_pk_bf16(s0[14], s0[15]);
      permlane32_swap(a0, b0);
      permlane32_swap(a1, b1);
      permlane32_swap(a2, b2);
      permlane32_swap(a3, b3);
      union { uint32_t u[4]; bf16x8 v; } ua, ub, uc, ud;
      ua.u[0] = a0; ua.u[1] = a1; ua.u[2] = b0; ua.u[3] = b1; pa[0] = ua.v;
      ub.u[0] = a2; ub.u[1] = a3; ub.u[2] = b2; ub.u[3] = b3; pa[1] = ub.v;
      uint32_t c0 = cvt_pk_bf16(s1[0], s1[1]),   d0 = cvt_pk_bf16(s1[4], s1[5]);
      uint32_t c1 = cvt_pk_bf16(s1[2], s1[3]),   d1 = cvt_pk_bf16(s1[6], s1[7]);
      uint32_t c2 = cvt_pk_bf16(s1[8], s1[9]),   d2 = cvt_pk_bf16(s1[12], s1[13]);
      uint32_t c3 = cvt_pk_bf16(s1[10], s1[11]), d3 = cvt_pk_bf16(s1[14], s1[15]);
      permlane32_swap(c0, d0);
      permlane32_swap(c1, d1);
      permlane32_swap(c2, d2);
      permlane32_swap(c3, d3);
      uc.u[0] = c0; uc.u[1] = c1; uc.u[2] = d0; uc.u[3] = d1; pa[2] = uc.v;
      ud.u[0] = c2; ud.u[1] = c3; ud.u[2] = d2; ud.u[3] = d3; pa[3] = ud.v;
    }

    // O += P * V  (B-operand: lane holds V^T[db*32 + l31][tt*16 + hi*8 + j])
    __builtin_amdgcn_s_setprio(1);
#pragma unroll
    for (int tt = 0; tt < 4; ++tt) {
      {
        const int row = l31;
        const int ch = (tt * 2 + hi) ^ (row & 7);
        const bf16x8 vf = *reinterpret_cast<const bf16x8*>(
            reinterpret_cast<const char*>(&lV[cur][0]) + row * 128 + ch * 16);
        o0 = mfma32_bf16(pa[tt], vf, o0);
      }
      {
        const int row = 32 + l31;
        const int ch = (tt * 2 + hi) ^ (row & 7);
        const bf16x8 vf = *reinterpret_cast<const bf16x8*>(
            reinterpret_cast<const char*>(&lV[cur][0]) + row * 128 + ch * 16);
        o1 = mfma32_bf16(pa[tt], vf, o1);
      }
    }
    __builtin_amdgcn_s_setprio(0);

    __syncthreads();
    cur ^= 1;
  }

  // combine the two k-halves of the denominator (lane l <-> l^32, same q)
  const float rs = (rs0 + rs1) + (rs2 + rs3);
  uint32_t ra = __builtin_bit_cast(uint32_t, rs), rb2 = ra;
  permlane32_swap(ra, rb2);
  const float tot = __builtin_bit_cast(float, ra) + __builtin_bit_cast(float, rb2);
  const float rinv = 1.0f / tot;

  const int b = bh >> 4, h = bh & 15;
#pragma unroll
  for (int r = 0; r < 16; ++r) {
    const int qr = (r & 3) + 8 * (r >> 2) + 4 * hi;
    const float inv = __shfl(rinv, qr, 64);   // lane qr holds denom for row qr
    const size_t grow = (size_t)(b * SEQ + q0w + qr) * CH + h * DH;
    O[grow + l31]      = to_bf16(o0[r] * inv);
    O[grow + 32 + l31] = to_bf16(o1[r] * inv);
  }
}

// ---------------- launch ----------------

extern "C" void kernel_launch(void* const* d_in, const int* in_sizes, int n_in,
                              void* d_out, int out_size, void* d_ws, size_t ws_size,
                              hipStream_t stream) {
  const float* x     = (const float*)d_in[0];
  const float* w_qkv = (const float*)d_in[1];
  const float* w_out = (const float*)d_in[2];
  const float* b_out = (const float*)d_in[3];
  float* out = (float*)d_out;

  char* ws = (char*)d_ws;
  bf16_t* xb    = (bf16_t*)(ws);                       // 16 MB  [8192][1024]
  bf16_t* wqkvT = (bf16_t*)(ws + 16777216);            // 6 MB   [3072][1024]
  bf16_t* woT   = (bf16_t*)(ws + 23068672);            // 2 MB   [1024][1024]
  bf16_t* Qb    = (bf16_t*)(ws + 25165824);            // 16 MB  [64][2048][64]
  bf16_t* Kb    = (bf16_t*)(ws + 41943040);            // 16 MB  [64][2048][64]
  bf16_t* Vb    = (bf16_t*)(ws + 58720256);            // 16 MB  [64][64][2048]
  bf16_t* Ab    = xb;                                  // alias: x no longer needed post-QKV

  prep<<<3072, 256, 0, stream>>>(x, xb, w_qkv, wqkvT, w_out, woT);

  gemm_bt<0><<<(3 * CH / 128) * (MTOT / 128), 256, 0, stream>>>(
      xb, wqkvT, CH, 3 * CH / 128, Qb, Kb, Vb, nullptr, nullptr);

  attn_fwd<<<1024, 256, 0, stream>>>(Qb, Kb, Vb, Ab);

  gemm_bt<1><<<(CH / 128) * (MTOT / 128), 256, 0, stream>>>(
      Ab, woT, CH, CH / 128, nullptr, nullptr, nullptr, b_out, out);
}